// Round 1
// baseline (587.975 us; speedup 1.0000x reference)
//
#include <hip/hip_runtime.h>
#include <hip/hip_bf16.h>

#define S 4096
#define DIM 1536
#define HEADS 12
#define HD 128
#define CHALF 64   // HD/2

typedef unsigned short u16;
typedef unsigned int u32;
typedef __attribute__((ext_vector_type(8))) short bf16x8;
typedef __attribute__((ext_vector_type(4))) float f32x4;

__device__ __forceinline__ u16 f2b(float f) {
    u32 u = __float_as_uint(f);
    u32 r = (u + 0x7fffu + ((u >> 16) & 1u)) >> 16;
    return (u16)r;
}
__device__ __forceinline__ float b2f(u16 b) {
    return __uint_as_float(((u32)b) << 16);
}

// ---------------- fp32 -> bf16 conversion ----------------
__global__ void k_cvt(const float4* __restrict__ src, ushort4* __restrict__ dst, int n4) {
    int i = blockIdx.x * 256 + threadIdx.x;
    if (i >= n4) return;
    float4 v = src[i];
    ushort4 o;
    o.x = f2b(v.x); o.y = f2b(v.y); o.z = f2b(v.z); o.w = f2b(v.w);
    dst[i] = o;
}

// ---------------- rope tables ----------------
__global__ void k_tables(const float* __restrict__ freqs, const int* __restrict__ grid_sizes,
                         float* __restrict__ cosT, float* __restrict__ sinT) {
    int idx = blockIdx.x * 256 + threadIdx.x;
    if (idx >= S * CHALF) return;
    int s = idx >> 6;
    int i = idx & 63;
    int H = grid_sizes[1], W = grid_sizes[2];
    int hw = H * W;
    int f = s / hw;
    int rem = s - f * hw;
    int h = rem / W;
    int w = rem - h * W;
    const int f0 = 22, f1 = 21;  // CHALF - 2*(CHALF/3), CHALF/3
    int pos = (i < f0) ? f : ((i < f0 + f1) ? h : w);
    float ang = freqs[pos * CHALF + i];
    cosT[idx] = cosf(ang);
    sinT[idx] = sinf(ang);
}

// ---------------- GEMM: C[M,N] = A[M,K] * W[N,K]^T + bias ----------------
// A,W bf16; C bf16 or fp32. Block 256 thr = 4 waves (2x2), tile 128x128, BK=32.
template<int OUT_BF16>
__global__ __launch_bounds__(256, 2) void k_gemm(const u16* __restrict__ A, const u16* __restrict__ W,
                                                 const float* __restrict__ bias, void* __restrict__ Cout,
                                                 int M, int N, int K) {
    __shared__ u16 As[128 * 40];
    __shared__ u16 Bs[128 * 40];
    int tid = threadIdx.x;
    int lane = tid & 63, wave = tid >> 6;
    int wm = wave >> 1, wn = wave & 1;
    int quad = lane >> 4, l16 = lane & 15;
    int rowBase = blockIdx.y * 128;
    int colBase = blockIdx.x * 128;

    f32x4 acc[4][4] = {};
    int sr = tid >> 2;
    int sc = (tid & 3) << 3;

    for (int kb = 0; kb < K; kb += 32) {
        __syncthreads();
        uint4 a0 = *(const uint4*)(A + (size_t)(rowBase + sr) * K + kb + sc);
        uint4 a1 = *(const uint4*)(A + (size_t)(rowBase + sr + 64) * K + kb + sc);
        uint4 w0 = *(const uint4*)(W + (size_t)(colBase + sr) * K + kb + sc);
        uint4 w1 = *(const uint4*)(W + (size_t)(colBase + sr + 64) * K + kb + sc);
        *(uint4*)(As + sr * 40 + sc) = a0;
        *(uint4*)(As + (sr + 64) * 40 + sc) = a1;
        *(uint4*)(Bs + sr * 40 + sc) = w0;
        *(uint4*)(Bs + (sr + 64) * 40 + sc) = w1;
        __syncthreads();

        bf16x8 a[4], b[4];
#pragma unroll
        for (int mi = 0; mi < 4; mi++)
            a[mi] = *(const bf16x8*)(As + (wm * 64 + mi * 16 + l16) * 40 + quad * 8);
#pragma unroll
        for (int ni = 0; ni < 4; ni++)
            b[ni] = *(const bf16x8*)(Bs + (wn * 64 + ni * 16 + l16) * 40 + quad * 8);
#pragma unroll
        for (int mi = 0; mi < 4; mi++)
#pragma unroll
            for (int ni = 0; ni < 4; ni++)
                acc[mi][ni] = __builtin_amdgcn_mfma_f32_16x16x32_bf16(a[mi], b[ni], acc[mi][ni], 0, 0, 0);
    }

#pragma unroll
    for (int mi = 0; mi < 4; mi++) {
#pragma unroll
        for (int ni = 0; ni < 4; ni++) {
            int col = colBase + wn * 64 + ni * 16 + l16;
            float bv = bias[col];
#pragma unroll
            for (int r = 0; r < 4; r++) {
                int row = rowBase + wm * 64 + mi * 16 + quad * 4 + r;
                float v = acc[mi][ni][r] + bv;
                if (OUT_BF16)
                    ((u16*)Cout)[(size_t)row * N + col] = f2b(v);
                else
                    ((float*)Cout)[(size_t)row * N + col] = v;
            }
        }
    }
}

// ---------------- RMSNorm + RoPE (in-place on bf16 rows) ----------------
__global__ __launch_bounds__(256) void k_normrope(u16* __restrict__ q, const float* __restrict__ g,
                                                  const float* __restrict__ cosT, const float* __restrict__ sinT) {
    int s = blockIdx.x;
    int tid = threadIdx.x;
    int lane = tid & 63, wave = tid >> 6;
    u32* row = (u32*)(q + (size_t)s * DIM);

    // 768 u32 words (pairs) per row; 3 per thread
    int w0 = tid, w1 = tid + 256, w2 = tid + 512;
    u32 p0 = row[w0], p1 = row[w1], p2 = row[w2];
    float e0 = b2f(p0 & 0xffff), o0 = b2f(p0 >> 16);
    float e1 = b2f(p1 & 0xffff), o1 = b2f(p1 >> 16);
    float e2 = b2f(p2 & 0xffff), o2 = b2f(p2 >> 16);
    float ss = e0 * e0 + o0 * o0 + e1 * e1 + o1 * o1 + e2 * e2 + o2 * o2;

    __shared__ float wsum[4];
    for (int off = 32; off; off >>= 1) ss += __shfl_down(ss, off);
    if (lane == 0) wsum[wave] = ss;
    __syncthreads();
    float tot = wsum[0] + wsum[1] + wsum[2] + wsum[3];
    float r = rsqrtf(tot * (1.0f / DIM) + 1e-6f);

    const float* cr = cosT + (size_t)s * CHALF;
    const float* sr = sinT + (size_t)s * CHALF;
#pragma unroll
    for (int j = 0; j < 3; j++) {
        int p = (j == 0) ? w0 : (j == 1) ? w1 : w2;
        float e = (j == 0) ? e0 : (j == 1) ? e1 : e2;
        float o = (j == 0) ? o0 : (j == 1) ? o1 : o2;
        int i = p & 63;
        float c = cr[i], sn = sr[i];
        e = e * r * g[2 * p];
        o = o * r * g[2 * p + 1];
        float ne = e * c - o * sn;
        float no = e * sn + o * c;
        row[p] = (u32)f2b(ne) | ((u32)f2b(no) << 16);
    }
}

// ---------------- transpose vb[S][DIM] -> vt[DIM][S] ----------------
__global__ void k_transpose(const u16* __restrict__ src, u16* __restrict__ dst) {
    __shared__ u16 t[32][33];
    int bx = blockIdx.x;  // DIM tiles
    int by = blockIdx.y;  // S tiles
    int tx = threadIdx.x, ty = threadIdx.y;
#pragma unroll
    for (int i = 0; i < 4; i++)
        t[ty + i * 8][tx] = src[(size_t)(by * 32 + ty + i * 8) * DIM + bx * 32 + tx];
    __syncthreads();
#pragma unroll
    for (int i = 0; i < 4; i++)
        dst[(size_t)(bx * 32 + ty + i * 8) * S + by * 32 + tx] = t[tx][ty + i * 8];
}

// ---------------- flash attention ----------------
// grid (S/64, HEADS), 256 thr = 4 waves; wave w handles q rows [q0+16w, q0+16w+16)
__global__ __launch_bounds__(256, 2) void k_attn(const u16* __restrict__ q, const u16* __restrict__ k,
                                                 const u16* __restrict__ vt, u16* __restrict__ out,
                                                 const int* __restrict__ seq_lens) {
    int h = blockIdx.y;
    int q0 = blockIdx.x * 64;
    int tid = threadIdx.x;
    int lane = tid & 63, wave = tid >> 6;
    int quad = lane >> 4, l16 = lane & 15;
    int seqlen = seq_lens[0];

    __shared__ u16 Ks[64 * 136];   // [64 keys][128 + 8 pad]
    __shared__ u16 Vs[128 * 72];   // [128 d][64 keys + 8 pad]
    __shared__ u16 Ps[4][16 * 72]; // per wave [16 q][64 keys + 8 pad]

    // Q fragments, kept in registers for all k-tiles
    bf16x8 qf[4];
    int qrow = q0 + wave * 16 + l16;
#pragma unroll
    for (int kk = 0; kk < 4; kk++)
        qf[kk] = *(const bf16x8*)(q + (size_t)qrow * DIM + h * HD + kk * 32 + quad * 8);

    f32x4 o_acc[8] = {};
    float m_i[4], l_i[4];
#pragma unroll
    for (int r = 0; r < 4; r++) { m_i[r] = -INFINITY; l_i[r] = 0.f; }

    const float scale = 0.08838834764831845f;  // 1/sqrt(128)

    for (int kt = 0; kt < S; kt += 64) {
        __syncthreads();
        {
            int r = tid >> 4, ccol = (tid & 15) * 8;
#pragma unroll
            for (int it = 0; it < 4; it++) {
                uint4 kv = *(const uint4*)(k + (size_t)(kt + r + it * 16) * DIM + h * HD + ccol);
                *(uint4*)(Ks + (r + it * 16) * 136 + ccol) = kv;
            }
            int dr = tid >> 3, dc = (tid & 7) * 8;
#pragma unroll
            for (int it = 0; it < 4; it++) {
                uint4 vv = *(const uint4*)(vt + (size_t)(h * HD + dr + it * 32) * S + kt + dc);
                *(uint4*)(Vs + (dr + it * 32) * 72 + dc) = vv;
            }
        }
        __syncthreads();

        // QK^T -> 16 q rows x 64 keys per wave
        f32x4 sc4[4] = {};
#pragma unroll
        for (int ni = 0; ni < 4; ni++) {
#pragma unroll
            for (int kk = 0; kk < 4; kk++) {
                bf16x8 bfrag = *(const bf16x8*)(Ks + (ni * 16 + l16) * 136 + kk * 32 + quad * 8);
                sc4[ni] = __builtin_amdgcn_mfma_f32_16x16x32_bf16(qf[kk], bfrag, sc4[ni], 0, 0, 0);
            }
        }

        // scale + mask + row max (rows m = quad*4+r, spread over 16 lanes of the quad)
        float alpha[4];
#pragma unroll
        for (int r = 0; r < 4; r++) {
            float mx = -1e30f;
#pragma unroll
            for (int ni = 0; ni < 4; ni++) {
                int kg = kt + ni * 16 + l16;
                float v = sc4[ni][r] * scale;
                v = (kg < seqlen) ? v : -1e30f;
                sc4[ni][r] = v;
                mx = fmaxf(mx, v);
            }
            mx = fmaxf(mx, __shfl_xor(mx, 1));
            mx = fmaxf(mx, __shfl_xor(mx, 2));
            mx = fmaxf(mx, __shfl_xor(mx, 4));
            mx = fmaxf(mx, __shfl_xor(mx, 8));
            float mnew = fmaxf(m_i[r], mx);
            alpha[r] = __expf(m_i[r] - mnew);
            m_i[r] = mnew;
            float s = 0.f;
#pragma unroll
            for (int ni = 0; ni < 4; ni++) {
                float p = __expf(sc4[ni][r] - mnew);
                sc4[ni][r] = p;
                s += p;
            }
            s += __shfl_xor(s, 1);
            s += __shfl_xor(s, 2);
            s += __shfl_xor(s, 4);
            s += __shfl_xor(s, 8);
            l_i[r] = l_i[r] * alpha[r] + s;
        }
        // rescale O accumulators
#pragma unroll
        for (int t2 = 0; t2 < 8; t2++)
#pragma unroll
            for (int r = 0; r < 4; r++) o_acc[t2][r] *= alpha[r];

        // P: C-layout -> LDS -> A-layout
#pragma unroll
        for (int ni = 0; ni < 4; ni++)
#pragma unroll
            for (int r = 0; r < 4; r++)
                Ps[wave][(quad * 4 + r) * 72 + ni * 16 + l16] = f2b(sc4[ni][r]);
        __syncthreads();

        bf16x8 pf0 = *(const bf16x8*)(Ps[wave] + l16 * 72 + quad * 8);
        bf16x8 pf1 = *(const bf16x8*)(Ps[wave] + l16 * 72 + 32 + quad * 8);
#pragma unroll
        for (int t2 = 0; t2 < 8; t2++) {
            bf16x8 vf0 = *(const bf16x8*)(Vs + (t2 * 16 + l16) * 72 + quad * 8);
            bf16x8 vf1 = *(const bf16x8*)(Vs + (t2 * 16 + l16) * 72 + 32 + quad * 8);
            o_acc[t2] = __builtin_amdgcn_mfma_f32_16x16x32_bf16(pf0, vf0, o_acc[t2], 0, 0, 0);
            o_acc[t2] = __builtin_amdgcn_mfma_f32_16x16x32_bf16(pf1, vf1, o_acc[t2], 0, 0, 0);
        }
    }

    // epilogue: divide by l, write bf16
#pragma unroll
    for (int t2 = 0; t2 < 8; t2++) {
#pragma unroll
        for (int r = 0; r < 4; r++) {
            int row = q0 + wave * 16 + quad * 4 + r;
            int d = t2 * 16 + l16;
            out[(size_t)row * DIM + h * HD + d] = f2b(o_acc[t2][r] / l_i[r]);
        }
    }
}

extern "C" void kernel_launch(void* const* d_in, const int* in_sizes, int n_in,
                              void* d_out, int out_size, void* d_ws, size_t ws_size,
                              hipStream_t stream) {
    const float* x = (const float*)d_in[0];
    const int* seq_lens = (const int*)d_in[1];
    const int* grid_sizes = (const int*)d_in[2];
    const float* freqs = (const float*)d_in[3];
    const float* Wq = (const float*)d_in[5];
    const float* bq = (const float*)d_in[6];
    const float* Wk = (const float*)d_in[7];
    const float* bk = (const float*)d_in[8];
    const float* Wv = (const float*)d_in[9];
    const float* bv = (const float*)d_in[10];
    const float* Wo = (const float*)d_in[11];
    const float* bo = (const float*)d_in[12];
    const float* gq = (const float*)d_in[13];
    const float* gk = (const float*)d_in[14];
    float* out = (float*)d_out;

    char* w = (char*)d_ws;
    u16* xb = (u16*)w;  w += (size_t)S * DIM * 2;
    u16* qb = (u16*)w;  w += (size_t)S * DIM * 2;
    u16* kb = (u16*)w;  w += (size_t)S * DIM * 2;
    u16* vb = (u16*)w;  w += (size_t)S * DIM * 2;
    u16* vt = (u16*)w;  w += (size_t)S * DIM * 2;
    u16* ab = (u16*)w;  w += (size_t)S * DIM * 2;
    u16* Wqb = (u16*)w; w += (size_t)DIM * DIM * 2;
    u16* Wkb = (u16*)w; w += (size_t)DIM * DIM * 2;
    u16* Wvb = (u16*)w; w += (size_t)DIM * DIM * 2;
    u16* Wob = (u16*)w; w += (size_t)DIM * DIM * 2;
    float* cosT = (float*)w; w += (size_t)S * CHALF * 4;
    float* sinT = (float*)w; w += (size_t)S * CHALF * 4;

    int n4x = S * DIM / 4;        // 1,572,864
    int n4w = DIM * DIM / 4;      // 589,824
    k_cvt<<<n4x / 256, 256, 0, stream>>>((const float4*)x, (ushort4*)xb, n4x);
    k_cvt<<<n4w / 256, 256, 0, stream>>>((const float4*)Wq, (ushort4*)Wqb, n4w);
    k_cvt<<<n4w / 256, 256, 0, stream>>>((const float4*)Wk, (ushort4*)Wkb, n4w);
    k_cvt<<<n4w / 256, 256, 0, stream>>>((const float4*)Wv, (ushort4*)Wvb, n4w);
    k_cvt<<<n4w / 256, 256, 0, stream>>>((const float4*)Wo, (ushort4*)Wob, n4w);
    k_tables<<<(S * CHALF + 255) / 256, 256, 0, stream>>>(freqs, grid_sizes, cosT, sinT);

    dim3 gg(DIM / 128, S / 128);  // (12, 32)
    k_gemm<1><<<gg, 256, 0, stream>>>(xb, Wqb, bq, qb, S, DIM, DIM);
    k_gemm<1><<<gg, 256, 0, stream>>>(xb, Wkb, bk, kb, S, DIM, DIM);
    k_gemm<1><<<gg, 256, 0, stream>>>(xb, Wvb, bv, vb, S, DIM, DIM);

    k_normrope<<<S, 256, 0, stream>>>(qb, gq, cosT, sinT);
    k_normrope<<<S, 256, 0, stream>>>(kb, gk, cosT, sinT);

    k_transpose<<<dim3(DIM / 32, S / 32), dim3(32, 8), 0, stream>>>(vb, vt);

    k_attn<<<dim3(S / 64, HEADS), 256, 0, stream>>>(qb, kb, vt, ab, seq_lens);

    k_gemm<0><<<gg, 256, 0, stream>>>(ab, Wob, bo, out, S, DIM, DIM);
}

// Round 2
// 514.160 us; speedup vs baseline: 1.1436x; 1.1436x over previous
//
#include <hip/hip_runtime.h>
#include <hip/hip_bf16.h>

#define S 4096
#define DIM 1536
#define HEADS 12
#define HD 128
#define CHALF 64   // HD/2
#define NQKV 4608  // 3*DIM

typedef unsigned short u16;
typedef unsigned int u32;
typedef __attribute__((ext_vector_type(8))) short bf16x8;
typedef __attribute__((ext_vector_type(4))) float f32x4;

__device__ __forceinline__ u16 f2b(float f) {  // RNE
    u32 u = __float_as_uint(f);
    u32 r = (u + 0x7fffu + ((u >> 16) & 1u)) >> 16;
    return (u16)r;
}
__device__ __forceinline__ float b2f(u16 b) {
    return __uint_as_float(((u32)b) << 16);
}
// cheap round-half-up pack of two non-negative floats into packed bf16x2
__device__ __forceinline__ u32 pack2(float a, float b) {
    u32 lo = (__float_as_uint(a) + 0x8000u) >> 16;
    u32 hi = (__float_as_uint(b) + 0x8000u) & 0xffff0000u;
    return lo | hi;
}

// ---------------- fp32 -> bf16 conversion ----------------
__global__ void k_cvt(const float4* __restrict__ src, ushort4* __restrict__ dst, int n4) {
    int i = blockIdx.x * 256 + threadIdx.x;
    if (i >= n4) return;
    float4 v = src[i];
    ushort4 o;
    o.x = f2b(v.x); o.y = f2b(v.y); o.z = f2b(v.z); o.w = f2b(v.w);
    dst[i] = o;
}

// ---------------- rope tables ----------------
__global__ void k_tables(const float* __restrict__ freqs, const int* __restrict__ grid_sizes,
                         float* __restrict__ cosT, float* __restrict__ sinT) {
    int idx = blockIdx.x * 256 + threadIdx.x;
    if (idx >= S * CHALF) return;
    int s = idx >> 6;
    int i = idx & 63;
    int H = grid_sizes[1], W = grid_sizes[2];
    int hw = H * W;
    int f = s / hw;
    int rem = s - f * hw;
    int h = rem / W;
    int w = rem - h * W;
    const int f0 = 22, f1 = 21;
    int pos = (i < f0) ? f : ((i < f0 + f1) ? h : w);
    float ang = freqs[pos * CHALF + i];
    cosT[idx] = cosf(ang);
    sinT[idx] = sinf(ang);
}

// ---------------- GEMM: C[M,N] = A[M,K] * W[N,K]^T + bias ----------------
template<int TM, int OUT_BF16, int QKV>
__global__ __launch_bounds__(256, 2) void k_gemm(const u16* __restrict__ A, const u16* __restrict__ W,
                                                 const float* __restrict__ b0, const float* __restrict__ b1,
                                                 const float* __restrict__ b2,
                                                 void* __restrict__ Cout, int N, int K, int ldc) {
    __shared__ u16 As[TM * 40];
    __shared__ u16 Bs[128 * 40];
    int tid = threadIdx.x;
    int lane = tid & 63, wave = tid >> 6;
    int wm = wave >> 1, wn = wave & 1;
    int quad = lane >> 4, l16 = lane & 15;
    int rowBase = blockIdx.y * TM;
    int colBase = blockIdx.x * 128;

    constexpr int MI = (TM == 128) ? 4 : 2;
    f32x4 acc[MI][4] = {};

    for (int kb = 0; kb < K; kb += 32) {
        __syncthreads();
        if (TM == 128) {
            int sr = tid >> 2, sc = (tid & 3) << 3;
            uint4 a0 = *(const uint4*)(A + (size_t)(rowBase + sr) * K + kb + sc);
            uint4 a1 = *(const uint4*)(A + (size_t)(rowBase + sr + 64) * K + kb + sc);
            uint4 w0 = *(const uint4*)(W + (size_t)(colBase + sr) * K + kb + sc);
            uint4 w1 = *(const uint4*)(W + (size_t)(colBase + sr + 64) * K + kb + sc);
            *(uint4*)(As + sr * 40 + sc) = a0;
            *(uint4*)(As + (sr + 64) * 40 + sc) = a1;
            *(uint4*)(Bs + sr * 40 + sc) = w0;
            *(uint4*)(Bs + (sr + 64) * 40 + sc) = w1;
        } else {
            int sr = tid >> 2, sc = (tid & 3) << 3;
            uint4 a0 = *(const uint4*)(A + (size_t)(rowBase + sr) * K + kb + sc);
            uint4 w0 = *(const uint4*)(W + (size_t)(colBase + sr) * K + kb + sc);
            uint4 w1 = *(const uint4*)(W + (size_t)(colBase + sr + 64) * K + kb + sc);
            *(uint4*)(As + sr * 40 + sc) = a0;
            *(uint4*)(Bs + sr * 40 + sc) = w0;
            *(uint4*)(Bs + (sr + 64) * 40 + sc) = w1;
        }
        __syncthreads();

        bf16x8 a[MI], b[4];
#pragma unroll
        for (int mi = 0; mi < MI; mi++) {
            int row = (TM == 128) ? (wm * 64 + mi * 16 + l16) : (wm * 32 + mi * 16 + l16);
            a[mi] = *(const bf16x8*)(As + row * 40 + quad * 8);
        }
#pragma unroll
        for (int ni = 0; ni < 4; ni++)
            b[ni] = *(const bf16x8*)(Bs + (wn * 64 + ni * 16 + l16) * 40 + quad * 8);
#pragma unroll
        for (int mi = 0; mi < MI; mi++)
#pragma unroll
            for (int ni = 0; ni < 4; ni++)
                acc[mi][ni] = __builtin_amdgcn_mfma_f32_16x16x32_bf16(a[mi], b[ni], acc[mi][ni], 0, 0, 0);
    }

#pragma unroll
    for (int mi = 0; mi < MI; mi++) {
#pragma unroll
        for (int ni = 0; ni < 4; ni++) {
            int col = colBase + wn * 64 + ni * 16 + l16;
            float bv;
            if (QKV) {
                int third = colBase / DIM;  // block's 128 cols lie within one third
                const float* bp = (third == 0) ? b0 : ((third == 1) ? b1 : b2);
                bv = bp[col - third * DIM];
            } else {
                bv = b0[col];
            }
#pragma unroll
            for (int r = 0; r < 4; r++) {
                int row = rowBase + ((TM == 128) ? wm * 64 : wm * 32) + mi * 16 + quad * 4 + r;
                float v = acc[mi][ni][r] + bv;
                if (OUT_BF16)
                    ((u16*)Cout)[(size_t)row * ldc + col] = f2b(v);
                else
                    ((float*)Cout)[(size_t)row * ldc + col] = v;
            }
        }
    }
}

// ---------------- RMSNorm + RoPE (in-place on bf16 rows of qkv, row stride 4608) ----------------
__global__ __launch_bounds__(256) void k_normrope(u16* __restrict__ base, const float* __restrict__ g,
                                                  const float* __restrict__ cosT, const float* __restrict__ sinT,
                                                  float scale) {
    int s = blockIdx.x;
    int tid = threadIdx.x;
    int lane = tid & 63, wave = tid >> 6;
    u32* row = (u32*)(base + (size_t)s * NQKV);

    int w0 = tid, w1 = tid + 256, w2 = tid + 512;
    u32 p0 = row[w0], p1 = row[w1], p2 = row[w2];
    float e0 = b2f(p0 & 0xffff), o0 = b2f(p0 >> 16);
    float e1 = b2f(p1 & 0xffff), o1 = b2f(p1 >> 16);
    float e2 = b2f(p2 & 0xffff), o2 = b2f(p2 >> 16);
    float ss = e0 * e0 + o0 * o0 + e1 * e1 + o1 * o1 + e2 * e2 + o2 * o2;

    __shared__ float wsum[4];
    for (int off = 32; off; off >>= 1) ss += __shfl_down(ss, off);
    if (lane == 0) wsum[wave] = ss;
    __syncthreads();
    float tot = wsum[0] + wsum[1] + wsum[2] + wsum[3];
    float r = rsqrtf(tot * (1.0f / DIM) + 1e-6f) * scale;

    const float* cr = cosT + (size_t)s * CHALF;
    const float* sr = sinT + (size_t)s * CHALF;
#pragma unroll
    for (int j = 0; j < 3; j++) {
        int p = (j == 0) ? w0 : (j == 1) ? w1 : w2;
        float e = (j == 0) ? e0 : (j == 1) ? e1 : e2;
        float o = (j == 0) ? o0 : (j == 1) ? o1 : o2;
        int i = p & 63;
        float c = cr[i], sn = sr[i];
        e = e * r * g[2 * p];
        o = o * r * g[2 * p + 1];
        float ne = e * c - o * sn;
        float no = e * sn + o * c;
        row[p] = (u32)f2b(ne) | ((u32)f2b(no) << 16);
    }
}

// ---------------- transpose v-slice of qkv -> vt[DIM][S] ----------------
__global__ void k_transpose(const u16* __restrict__ src, u16* __restrict__ dst) {
    __shared__ u16 t[32][33];
    int bx = blockIdx.x;
    int by = blockIdx.y;
    int tx = threadIdx.x, ty = threadIdx.y;
#pragma unroll
    for (int i = 0; i < 4; i++)
        t[ty + i * 8][tx] = src[(size_t)(by * 32 + ty + i * 8) * NQKV + bx * 32 + tx];
    __syncthreads();
#pragma unroll
    for (int i = 0; i < 4; i++)
        dst[(size_t)(bx * 32 + ty + i * 8) * S + by * 32 + tx] = t[tx][ty + i * 8];
}

// ---------------- flash attention, S^T formulation, split-K over 2 key halves ----------------
__global__ __launch_bounds__(256, 2) void k_attn(const u16* __restrict__ qkv, const u16* __restrict__ vt,
                                                 u16* __restrict__ O0, u16* __restrict__ O1,
                                                 float2* __restrict__ ml,
                                                 const int* __restrict__ seq_lens) {
    int h = blockIdx.y;
    int q0 = blockIdx.x * 128;
    int p = blockIdx.z;
    int kh0 = p * (S / 2);
    int tid = threadIdx.x;
    int lane = tid & 63, wave = tid >> 6;
    int quad = lane >> 4, l16 = lane & 15;
    int seqlen = seq_lens[0];
    u16* Op = p ? O1 : O0;

    __shared__ u16 Ks[64 * 136];   // [64 keys][128 + 8 pad]
    __shared__ u16 Vs[128 * 72];   // [128 d][64 keys + 8 pad]

    bf16x8 qf[2][4];
#pragma unroll
    for (int qs = 0; qs < 2; qs++) {
        int qrow = q0 + wave * 32 + qs * 16 + l16;
#pragma unroll
        for (int kk = 0; kk < 4; kk++)
            qf[qs][kk] = *(const bf16x8*)(qkv + (size_t)qrow * NQKV + h * HD + kk * 32 + quad * 8);
    }

    f32x4 o_acc[2][8] = {};
    float m_i[2] = {-1e30f, -1e30f}, l_i[2] = {0.f, 0.f};

    for (int kt = 0; kt < S / 2; kt += 64) {
        int kbase = kh0 + kt;
        __syncthreads();
        {
            int r = tid >> 4, ccol = (tid & 15) * 8;
#pragma unroll
            for (int it = 0; it < 4; it++) {
                uint4 kv = *(const uint4*)(qkv + (size_t)(kbase + r + it * 16) * NQKV + DIM + h * HD + ccol);
                *(uint4*)(Ks + (r + it * 16) * 136 + ccol) = kv;
            }
            int dr = tid >> 3, dc = (tid & 7) * 8;
#pragma unroll
            for (int it = 0; it < 4; it++) {
                uint4 vv = *(const uint4*)(vt + (size_t)(h * HD + dr + it * 32) * S + kbase + dc);
                *(uint4*)(Vs + (dr + it * 32) * 72 + dc) = vv;
            }
        }
        __syncthreads();

        // S^T = K * Q^T, K-frags shared across both q-sets
        f32x4 sc[2][4] = {};
#pragma unroll
        for (int ni = 0; ni < 4; ni++) {
#pragma unroll
            for (int kk = 0; kk < 4; kk++) {
                bf16x8 kf = *(const bf16x8*)(Ks + (ni * 16 + l16) * 136 + kk * 32 + quad * 8);
                sc[0][ni] = __builtin_amdgcn_mfma_f32_16x16x32_bf16(kf, qf[0][kk], sc[0][ni], 0, 0, 0);
                sc[1][ni] = __builtin_amdgcn_mfma_f32_16x16x32_bf16(kf, qf[1][kk], sc[1][ni], 0, 0, 0);
            }
        }

        bf16x8 pfrag[2][2];
#pragma unroll
        for (int qs = 0; qs < 2; qs++) {
            float mx = -1e30f;
#pragma unroll
            for (int ni = 0; ni < 4; ni++) {
#pragma unroll
                for (int r = 0; r < 4; r++) {
                    int kg = kbase + ni * 16 + quad * 4 + r;
                    float v = sc[qs][ni][r];
                    v = (kg < seqlen) ? v : -1e30f;
                    sc[qs][ni][r] = v;
                    mx = fmaxf(mx, v);
                }
            }
            mx = fmaxf(mx, __shfl_xor(mx, 16));
            mx = fmaxf(mx, __shfl_xor(mx, 32));
            float mnew = fmaxf(m_i[qs], mx);
            float alpha = exp2f(m_i[qs] - mnew);
            m_i[qs] = mnew;
            float ssum = 0.f;
#pragma unroll
            for (int ni = 0; ni < 4; ni++) {
#pragma unroll
                for (int r = 0; r < 4; r++) {
                    float pv = exp2f(sc[qs][ni][r] - mnew);
                    sc[qs][ni][r] = pv;
                    ssum += pv;
                }
            }
            ssum += __shfl_xor(ssum, 16);
            ssum += __shfl_xor(ssum, 32);
            l_i[qs] = l_i[qs] * alpha + ssum;
#pragma unroll
            for (int t2 = 0; t2 < 8; t2++)
#pragma unroll
                for (int r = 0; r < 4; r++) o_acc[qs][t2][r] *= alpha;

            u32 pk[4][2];
#pragma unroll
            for (int ni = 0; ni < 4; ni++) {
                pk[ni][0] = pack2(sc[qs][ni][0], sc[qs][ni][1]);
                pk[ni][1] = pack2(sc[qs][ni][2], sc[qs][ni][3]);
            }
            int sA = ((quad & 1) * 2) * 16 + l16;
            int sB = sA + 16;
            bool hi = (quad >= 2);
#pragma unroll
            for (int j = 0; j < 2; j++) {
                u32 a0 = (u32)__shfl((int)pk[2 * j][0], sA);
                u32 a1 = (u32)__shfl((int)pk[2 * j][1], sA);
                u32 a2 = (u32)__shfl((int)pk[2 * j][0], sB);
                u32 a3 = (u32)__shfl((int)pk[2 * j][1], sB);
                u32 c0 = (u32)__shfl((int)pk[2 * j + 1][0], sA);
                u32 c1 = (u32)__shfl((int)pk[2 * j + 1][1], sA);
                u32 c2 = (u32)__shfl((int)pk[2 * j + 1][0], sB);
                u32 c3 = (u32)__shfl((int)pk[2 * j + 1][1], sB);
                union { u32 u[4]; bf16x8 v; } cvt;
                cvt.u[0] = hi ? c0 : a0;
                cvt.u[1] = hi ? c1 : a1;
                cvt.u[2] = hi ? c2 : a2;
                cvt.u[3] = hi ? c3 : a3;
                pfrag[qs][j] = cvt.v;
            }
        }

        // O^T += V^T * P^T, V-frags shared across both q-sets
#pragma unroll
        for (int t2 = 0; t2 < 8; t2++) {
            bf16x8 vf0 = *(const bf16x8*)(Vs + (t2 * 16 + l16) * 72 + quad * 8);
            bf16x8 vf1 = *(const bf16x8*)(Vs + (t2 * 16 + l16) * 72 + 32 + quad * 8);
#pragma unroll
            for (int qs = 0; qs < 2; qs++) {
                o_acc[qs][t2] = __builtin_amdgcn_mfma_f32_16x16x32_bf16(vf0, pfrag[qs][0], o_acc[qs][t2], 0, 0, 0);
                o_acc[qs][t2] = __builtin_amdgcn_mfma_f32_16x16x32_bf16(vf1, pfrag[qs][1], o_acc[qs][t2], 0, 0, 0);
            }
        }
    }

#pragma unroll
    for (int qs = 0; qs < 2; qs++) {
        float inv = 1.0f / l_i[qs];
        int qrow = q0 + wave * 32 + qs * 16 + l16;
#pragma unroll
        for (int t2 = 0; t2 < 8; t2++) {
#pragma unroll
            for (int r = 0; r < 4; r++) {
                int d = t2 * 16 + quad * 4 + r;
                Op[(size_t)qrow * DIM + h * HD + d] = f2b(o_acc[qs][t2][r] * inv);
            }
        }
        if (quad == 0)
            ml[((size_t)p * HEADS + h) * S + qrow] = make_float2(m_i[qs], l_i[qs]);
    }
}

// ---------------- combine split-K partials: ab = c0*O0 + c1*O1 (in-place over O0) ----------------
__global__ __launch_bounds__(384) void k_combine(u16* __restrict__ O0, const u16* __restrict__ O1,
                                                 const float2* __restrict__ ml) {
    int q = blockIdx.x;
    int tid = threadIdx.x;
    int h = tid >> 5;
    size_t base = (size_t)q * DIM + tid * 4;
    float2 ml0 = ml[(size_t)h * S + q];
    float2 ml1 = ml[((size_t)HEADS + h) * S + q];
    float M = fmaxf(ml0.x, ml1.x);
    float w0 = exp2f(ml0.x - M) * ml0.y;
    float w1 = exp2f(ml1.x - M) * ml1.y;
    float inv = 1.0f / (w0 + w1);
    float c0 = w0 * inv, c1 = w1 * inv;
    uint2 u0 = *(const uint2*)(O0 + base);
    uint2 u1 = *(const uint2*)(O1 + base);
    const u16* a = (const u16*)&u0;
    const u16* b = (const u16*)&u1;
    u16 o[4];
#pragma unroll
    for (int i = 0; i < 4; i++)
        o[i] = f2b(c0 * b2f(a[i]) + c1 * b2f(b[i]));
    *(uint2*)(O0 + base) = *(uint2*)o;
}

extern "C" void kernel_launch(void* const* d_in, const int* in_sizes, int n_in,
                              void* d_out, int out_size, void* d_ws, size_t ws_size,
                              hipStream_t stream) {
    const float* x = (const float*)d_in[0];
    const int* seq_lens = (const int*)d_in[1];
    const int* grid_sizes = (const int*)d_in[2];
    const float* freqs = (const float*)d_in[3];
    const float* Wq = (const float*)d_in[5];
    const float* bq = (const float*)d_in[6];
    const float* Wk = (const float*)d_in[7];
    const float* bk = (const float*)d_in[8];
    const float* Wv = (const float*)d_in[9];
    const float* bv = (const float*)d_in[10];
    const float* Wo = (const float*)d_in[11];
    const float* bo = (const float*)d_in[12];
    const float* gq = (const float*)d_in[13];
    const float* gk = (const float*)d_in[14];
    float* out = (float*)d_out;

    char* w = (char*)d_ws;
    u16* xb    = (u16*)w; w += (size_t)S * DIM * 2;
    u16* qkv   = (u16*)w; w += (size_t)S * NQKV * 2;
    u16* Wqkvb = (u16*)w; w += (size_t)3 * DIM * DIM * 2;
    u16* Wob   = (u16*)w; w += (size_t)DIM * DIM * 2;
    u16* ab    = (u16*)w; w += (size_t)S * DIM * 2;   // O-partial 0, combined in place
    u16* O1    = (u16*)w; w += (size_t)S * DIM * 2;
    float* cosT = (float*)w; w += (size_t)S * CHALF * 4;
    float* sinT = (float*)w; w += (size_t)S * CHALF * 4;
    float2* ml = (float2*)w; w += (size_t)2 * HEADS * S * 8;
    u16* vt = Wqkvb;  // alias: QKV weights dead after QKV GEMM; vt written after

    const float qscale = 0.08838834764831845f * 1.44269504088896341f;  // HD^-0.5 * log2(e)

    int n4x = S * DIM / 4;
    int n4w = DIM * DIM / 4;
    k_cvt<<<n4x / 256, 256, 0, stream>>>((const float4*)x, (ushort4*)xb, n4x);
    k_cvt<<<n4w / 256, 256, 0, stream>>>((const float4*)Wq, (ushort4*)Wqkvb, n4w);
    k_cvt<<<n4w / 256, 256, 0, stream>>>((const float4*)Wk, (ushort4*)(Wqkvb + (size_t)DIM * DIM), n4w);
    k_cvt<<<n4w / 256, 256, 0, stream>>>((const float4*)Wv, (ushort4*)(Wqkvb + (size_t)2 * DIM * DIM), n4w);
    k_cvt<<<n4w / 256, 256, 0, stream>>>((const float4*)Wo, (ushort4*)Wob, n4w);
    k_tables<<<(S * CHALF + 255) / 256, 256, 0, stream>>>(freqs, grid_sizes, cosT, sinT);

    k_gemm<128, 1, 1><<<dim3(NQKV / 128, S / 128), 256, 0, stream>>>(
        xb, Wqkvb, bq, bk, bv, qkv, NQKV, DIM, NQKV);

    k_normrope<<<S, 256, 0, stream>>>(qkv, gq, cosT, sinT, qscale);
    k_normrope<<<S, 256, 0, stream>>>(qkv + DIM, gk, cosT, sinT, 1.0f);

    k_transpose<<<dim3(DIM / 32, S / 32), dim3(32, 8), 0, stream>>>(qkv + 2 * DIM, vt);

    k_attn<<<dim3(S / 128, HEADS, 2), 256, 0, stream>>>(qkv, vt, ab, O1, ml, seq_lens);

    k_combine<<<S, 384, 0, stream>>>(ab, O1, ml);

    k_gemm<64, 0, 0><<<dim3(DIM / 128, S / 64), 256, 0, stream>>>(
        ab, Wob, bo, bo, bo, out, DIM, DIM, DIM);
}

// Round 3
// 429.852 us; speedup vs baseline: 1.3679x; 1.1961x over previous
//
#include <hip/hip_runtime.h>
#include <hip/hip_bf16.h>

#define S 4096
#define DIM 1536
#define HEADS 12
#define HD 128
#define CHALF 64   // HD/2
#define NQKV 4608  // 3*DIM

typedef unsigned short u16;
typedef unsigned int u32;
typedef __attribute__((ext_vector_type(8))) short bf16x8;
typedef __attribute__((ext_vector_type(4))) float f32x4;
typedef __attribute__((ext_vector_type(16))) float f32x16;

__device__ __forceinline__ u16 f2b(float f) {  // RNE
    u32 u = __float_as_uint(f);
    u32 r = (u + 0x7fffu + ((u >> 16) & 1u)) >> 16;
    return (u16)r;
}
__device__ __forceinline__ float b2f(u16 b) {
    return __uint_as_float(((u32)b) << 16);
}
// round-half-up pack of two non-negative floats into packed bf16x2
__device__ __forceinline__ u32 pack2(float a, float b) {
    u32 lo = (__float_as_uint(a) + 0x8000u) >> 16;
    u32 hi = (__float_as_uint(b) + 0x8000u) & 0xffff0000u;
    return lo | hi;
}
// async global->LDS DMA, 16 B per lane, LDS dest = wave-uniform base + lane*16
__device__ __forceinline__ void gld_lds16(const u16* g, u16* l) {
    __builtin_amdgcn_global_load_lds((const __attribute__((address_space(1))) void*)g,
                                     (__attribute__((address_space(3))) void*)l, 16, 0, 0);
}

// ---------------- fused fp32 -> bf16 conversion (x + 4 weights) ----------------
__global__ void k_cvt_all(const float4* __restrict__ x, const float4* __restrict__ wq,
                          const float4* __restrict__ wk, const float4* __restrict__ wv,
                          const float4* __restrict__ wo,
                          ushort4* __restrict__ xb, ushort4* __restrict__ wqkv,
                          ushort4* __restrict__ wob) {
    const int N4X = S * DIM / 4, N4W = DIM * DIM / 4;
    int i = blockIdx.x * 256 + threadIdx.x;
    const float4* src; ushort4* dst; int off;
    if (i < N4X) { src = x; dst = xb; off = i; }
    else {
        int j = i - N4X;
        int w = j / N4W; off = j - w * N4W;
        if (w == 0)      { src = wq; dst = wqkv; }
        else if (w == 1) { src = wk; dst = wqkv + N4W; }
        else if (w == 2) { src = wv; dst = wqkv + 2 * N4W; }
        else             { src = wo; dst = wob; }
    }
    float4 v = src[off];
    ushort4 o;
    o.x = f2b(v.x); o.y = f2b(v.y); o.z = f2b(v.z); o.w = f2b(v.w);
    dst[off] = o;
}

// ---------------- rope tables ----------------
__global__ void k_tables(const float* __restrict__ freqs, const int* __restrict__ grid_sizes,
                         float* __restrict__ cosT, float* __restrict__ sinT) {
    int idx = blockIdx.x * 256 + threadIdx.x;
    if (idx >= S * CHALF) return;
    int s = idx >> 6;
    int i = idx & 63;
    int H = grid_sizes[1], W = grid_sizes[2];
    int hw = H * W;
    int f = s / hw;
    int rem = s - f * hw;
    int h = rem / W;
    int w = rem - h * W;
    const int f0 = 22, f1 = 21;
    int pos = (i < f0) ? f : ((i < f0 + f1) ? h : w);
    float ang = freqs[pos * CHALF + i];
    cosT[idx] = cosf(ang);
    sinT[idx] = sinf(ang);
}

// ---------------- GEMM: C[M,N] = A[M,K] * W[N,K]^T + bias, m97 structure ----------------
// 128x128 tile, BK=32, 4 waves 2x2, global_load_lds staging into unpadded [128][32] LDS.
template<int OUT_BF16, int QKV>
__global__ __launch_bounds__(256, 2) void k_gemm(const u16* __restrict__ A, const u16* __restrict__ W,
                                                 const float* __restrict__ b0, const float* __restrict__ b1,
                                                 const float* __restrict__ b2,
                                                 void* __restrict__ Cout, int N, int K, int ldc) {
    __shared__ u16 As[128 * 32];
    __shared__ u16 Bs[128 * 32];
    int tid = threadIdx.x;
    int lane = tid & 63, wave = tid >> 6;
    int wm = wave >> 1, wn = wave & 1;
    int quad = lane >> 4, l16 = lane & 15;
    int rowBase = blockIdx.y * 128;
    int colBase = blockIdx.x * 128;
    int lr = lane >> 2, lc = (lane & 3) << 3;  // staging: lane -> row lr, col lc (8 u16 = 16 B)

    f32x4 acc[4][4] = {};

    for (int kb = 0; kb < K; kb += 32) {
        __syncthreads();
#pragma unroll
        for (int c = 0; c < 2; c++) {
            int rrel = wave * 32 + c * 16;
            gld_lds16(A + (size_t)(rowBase + rrel + lr) * K + kb + lc, As + rrel * 32);
            gld_lds16(W + (size_t)(colBase + rrel + lr) * K + kb + lc, Bs + rrel * 32);
        }
        __syncthreads();

        bf16x8 a[4], b[4];
#pragma unroll
        for (int mi = 0; mi < 4; mi++)
            a[mi] = *(const bf16x8*)(As + (wm * 64 + mi * 16 + l16) * 32 + quad * 8);
#pragma unroll
        for (int ni = 0; ni < 4; ni++)
            b[ni] = *(const bf16x8*)(Bs + (wn * 64 + ni * 16 + l16) * 32 + quad * 8);
#pragma unroll
        for (int mi = 0; mi < 4; mi++)
#pragma unroll
            for (int ni = 0; ni < 4; ni++)
                acc[mi][ni] = __builtin_amdgcn_mfma_f32_16x16x32_bf16(a[mi], b[ni], acc[mi][ni], 0, 0, 0);
    }

#pragma unroll
    for (int mi = 0; mi < 4; mi++) {
#pragma unroll
        for (int ni = 0; ni < 4; ni++) {
            int col = colBase + wn * 64 + ni * 16 + l16;
            float bv;
            if (QKV) {
                int third = colBase / DIM;
                const float* bp = (third == 0) ? b0 : ((third == 1) ? b1 : b2);
                bv = bp[col - third * DIM];
            } else {
                bv = b0[col];
            }
#pragma unroll
            for (int r = 0; r < 4; r++) {
                int row = rowBase + wm * 64 + mi * 16 + quad * 4 + r;
                float v = acc[mi][ni][r] + bv;
                if (OUT_BF16)
                    ((u16*)Cout)[(size_t)row * ldc + col] = f2b(v);
                else
                    ((float*)Cout)[(size_t)row * ldc + col] = v;
            }
        }
    }
}

// ---------------- RMSNorm + RoPE, fused q & k (grid.y selects) ----------------
__global__ __launch_bounds__(256) void k_normrope(u16* __restrict__ qkvp, const float* __restrict__ gq,
                                                  const float* __restrict__ gk,
                                                  const float* __restrict__ cosT, const float* __restrict__ sinT,
                                                  float qscale) {
    int s = blockIdx.x;
    int which = blockIdx.y;              // 0 = q slice, 1 = k slice
    const float* g = which ? gk : gq;
    float scale = which ? 1.0f : qscale;
    int tid = threadIdx.x;
    int lane = tid & 63, wave = tid >> 6;
    u32* row = (u32*)(qkvp + (size_t)s * NQKV + which * DIM);

    int w0 = tid, w1 = tid + 256, w2 = tid + 512;
    u32 p0 = row[w0], p1 = row[w1], p2 = row[w2];
    float e0 = b2f(p0 & 0xffff), o0 = b2f(p0 >> 16);
    float e1 = b2f(p1 & 0xffff), o1 = b2f(p1 >> 16);
    float e2 = b2f(p2 & 0xffff), o2 = b2f(p2 >> 16);
    float ss = e0 * e0 + o0 * o0 + e1 * e1 + o1 * o1 + e2 * e2 + o2 * o2;

    __shared__ float wsum[4];
    for (int off = 32; off; off >>= 1) ss += __shfl_down(ss, off);
    if (lane == 0) wsum[wave] = ss;
    __syncthreads();
    float tot = wsum[0] + wsum[1] + wsum[2] + wsum[3];
    float r = rsqrtf(tot * (1.0f / DIM) + 1e-6f) * scale;

    const float* cr = cosT + (size_t)s * CHALF;
    const float* sr = sinT + (size_t)s * CHALF;
#pragma unroll
    for (int j = 0; j < 3; j++) {
        int p = (j == 0) ? w0 : (j == 1) ? w1 : w2;
        float e = (j == 0) ? e0 : (j == 1) ? e1 : e2;
        float o = (j == 0) ? o0 : (j == 1) ? o1 : o2;
        int i = p & 63;
        float c = cr[i], sn = sr[i];
        e = e * r * g[2 * p];
        o = o * r * g[2 * p + 1];
        float ne = e * c - o * sn;
        float no = e * sn + o * c;
        row[p] = (u32)f2b(ne) | ((u32)f2b(no) << 16);
    }
}

// ---------------- transpose v-slice of qkv -> vt[DIM][S] ----------------
__global__ void k_transpose(const u16* __restrict__ src, u16* __restrict__ dst) {
    __shared__ u16 t[32][33];
    int bx = blockIdx.x;
    int by = blockIdx.y;
    int tx = threadIdx.x, ty = threadIdx.y;
#pragma unroll
    for (int i = 0; i < 4; i++)
        t[ty + i * 8][tx] = src[(size_t)(by * 32 + ty + i * 8) * NQKV + bx * 32 + tx];
    __syncthreads();
#pragma unroll
    for (int i = 0; i < 4; i++)
        dst[(size_t)(bx * 32 + ty + i * 8) * S + by * 32 + tx] = t[tx][ty + i * 8];
}

// ---------------- flash attention: 32x32x16 MFMA, fixed-max softmax, split-K/2 ----------------
// grid (S/128, HEADS, 2), 256 thr = 4 waves; wave handles 32 q columns.
// S^T = K*Q^T (A=K-frag from LDS, B=Q-frag in registers); O^T += V^T * P^T.
// Scores C-layout: col=q=lane&31, row=key=(reg&3)+8*(reg>>2)+4*(lane>>5) -> per-lane row sums,
// P^T B-frag assembled with 4 shfl_xor(32) per 32-key block.
#define FM 16.5f
__global__ __launch_bounds__(256, 3) void k_attn(const u16* __restrict__ qkv, const u16* __restrict__ vt,
                                                 u16* __restrict__ O0, u16* __restrict__ O1,
                                                 float* __restrict__ lT,
                                                 const int* __restrict__ seq_lens) {
    int h = blockIdx.y;
    int q0 = blockIdx.x * 128;
    int p = blockIdx.z;
    int kh0 = p * (S / 2);
    int tid = threadIdx.x;
    int lane = tid & 63, wave = tid >> 6;
    int l31 = lane & 31, hi = lane >> 5;
    int seqlen = seq_lens[0];
    u16* Op = p ? O1 : O0;

    __shared__ u16 Ks[64 * 136];   // [64 keys][128 d + 8 pad]
    __shared__ u16 Vs[128 * 88];   // [128 d][64 keys + 24 pad]

    int qrow = q0 + wave * 32 + l31;
    bf16x8 qf[8];
#pragma unroll
    for (int c = 0; c < 8; c++)
        qf[c] = *(const bf16x8*)(qkv + (size_t)qrow * NQKV + h * HD + c * 16 + hi * 8);

    f32x16 o_acc[4] = {};
    float lsum = 0.f;

    for (int kt = 0; kt < S / 2; kt += 64) {
        int kbase = kh0 + kt;
        __syncthreads();
        {
            // stage K: 64 rows x 128 u16 (coalesced 4x uint4 per thread)
            int r = tid >> 2, cc = (tid & 3) * 32;
            const u16* gk_ = qkv + (size_t)(kbase + r) * NQKV + DIM + h * HD + cc;
            u16* dk = Ks + r * 136 + cc;
#pragma unroll
            for (int u = 0; u < 4; u++)
                *(uint4*)(dk + u * 8) = *(const uint4*)(gk_ + u * 8);
            // stage V^T: 128 rows x 64 u16
            int dr = tid >> 3, dc = (tid & 7) * 8;
#pragma unroll
            for (int it = 0; it < 4; it++)
                *(uint4*)(Vs + (dr + it * 32) * 88 + dc) =
                    *(const uint4*)(vt + (size_t)(h * HD + dr + it * 32) * S + kbase + dc);
        }
        __syncthreads();

        f32x16 sc0 = {}, sc1 = {};
#pragma unroll
        for (int c = 0; c < 8; c++) {
            bf16x8 kf0 = *(const bf16x8*)(Ks + l31 * 136 + c * 16 + hi * 8);
            bf16x8 kf1 = *(const bf16x8*)(Ks + (32 + l31) * 136 + c * 16 + hi * 8);
            sc0 = __builtin_amdgcn_mfma_f32_32x32x16_bf16(kf0, qf[c], sc0, 0, 0, 0);
            sc1 = __builtin_amdgcn_mfma_f32_32x32x16_bf16(kf1, qf[c], sc1, 0, 0, 0);
        }

        bool tail = (kbase + 64 > seqlen);
        bf16x8 pfrag[4];
#pragma unroll
        for (int b = 0; b < 2; b++) {
            f32x16 s16 = b ? sc1 : sc0;
            u32 pk[4][2];
            if (!tail) {
#pragma unroll
                for (int g = 0; g < 4; g++) {
                    float e0 = __builtin_amdgcn_exp2f(s16[4 * g + 0] - FM);
                    float e1 = __builtin_amdgcn_exp2f(s16[4 * g + 1] - FM);
                    float e2 = __builtin_amdgcn_exp2f(s16[4 * g + 2] - FM);
                    float e3 = __builtin_amdgcn_exp2f(s16[4 * g + 3] - FM);
                    lsum += (e0 + e1) + (e2 + e3);
                    pk[g][0] = pack2(e0, e1);
                    pk[g][1] = pack2(e2, e3);
                }
            } else {
#pragma unroll
                for (int g = 0; g < 4; g++) {
                    float e[4];
#pragma unroll
                    for (int r = 0; r < 4; r++) {
                        int key = kbase + b * 32 + r + 8 * g + 4 * hi;
                        float v = __builtin_amdgcn_exp2f(s16[4 * g + r] - FM);
                        e[r] = (key < seqlen) ? v : 0.f;
                        lsum += e[r];
                    }
                    pk[g][0] = pack2(e[0], e[1]);
                    pk[g][1] = pack2(e[2], e[3]);
                }
            }
            // exchange across hi-halves -> B-frags (chunks of 16 keys)
#pragma unroll
            for (int cc = 0; cc < 2; cc++) {
                int g0 = 2 * cc, g1 = 2 * cc + 1;
                u32 own0 = hi ? pk[g1][0] : pk[g0][0];
                u32 own1 = hi ? pk[g1][1] : pk[g0][1];
                u32 snd0 = hi ? pk[g0][0] : pk[g1][0];
                u32 snd1 = hi ? pk[g0][1] : pk[g1][1];
                u32 rcv0 = (u32)__shfl_xor((int)snd0, 32);
                u32 rcv1 = (u32)__shfl_xor((int)snd1, 32);
                union { u32 u[4]; bf16x8 v; } cvt2;
                cvt2.u[0] = hi ? rcv0 : own0;
                cvt2.u[1] = hi ? rcv1 : own1;
                cvt2.u[2] = hi ? own0 : rcv0;
                cvt2.u[3] = hi ? own1 : rcv1;
                pfrag[b * 2 + cc] = cvt2.v;
            }
        }

        // O^T += V^T * P^T
#pragma unroll
        for (int db = 0; db < 4; db++) {
#pragma unroll
            for (int c4 = 0; c4 < 4; c4++) {
                bf16x8 vf = *(const bf16x8*)(Vs + (db * 32 + l31) * 88 + c4 * 16 + hi * 8);
                o_acc[db] = __builtin_amdgcn_mfma_f32_32x32x16_bf16(vf, pfrag[c4], o_acc[db], 0, 0, 0);
            }
        }
    }

    float l_all = lsum + __shfl_xor(lsum, 32);
    float linv = 1.0f / l_all;
#pragma unroll
    for (int db = 0; db < 4; db++) {
#pragma unroll
        for (int g = 0; g < 4; g++) {
            int d0 = db * 32 + 8 * g + 4 * hi;
            u16 o4[4];
#pragma unroll
            for (int r = 0; r < 4; r++)
                o4[r] = f2b(o_acc[db][4 * g + r] * linv);
            *(uint2*)(Op + (size_t)qrow * DIM + h * HD + d0) = *(const uint2*)o4;
        }
    }
    if (!hi) lT[((size_t)p * HEADS + h) * S + qrow] = l_all;
}

// ---------------- combine split-K partials: O0 = (l0*O0 + l1*O1)/(l0+l1), in place ----------------
__global__ __launch_bounds__(384) void k_combine(u16* __restrict__ O0, const u16* __restrict__ O1,
                                                 const float* __restrict__ lT) {
    int q = blockIdx.x;
    int tid = threadIdx.x;
    int h = tid >> 5;
    size_t base = (size_t)q * DIM + tid * 4;
    float l0 = lT[(size_t)h * S + q];
    float l1 = lT[(size_t)(HEADS + h) * S + q];
    float inv = 1.0f / (l0 + l1);
    float c0 = l0 * inv, c1 = l1 * inv;
    uint2 u0 = *(const uint2*)(O0 + base);
    uint2 u1 = *(const uint2*)(O1 + base);
    const u16* a = (const u16*)&u0;
    const u16* b = (const u16*)&u1;
    u16 o[4];
#pragma unroll
    for (int i = 0; i < 4; i++)
        o[i] = f2b(c0 * b2f(a[i]) + c1 * b2f(b[i]));
    *(uint2*)(O0 + base) = *(uint2*)o;
}

extern "C" void kernel_launch(void* const* d_in, const int* in_sizes, int n_in,
                              void* d_out, int out_size, void* d_ws, size_t ws_size,
                              hipStream_t stream) {
    const float* x = (const float*)d_in[0];
    const int* seq_lens = (const int*)d_in[1];
    const int* grid_sizes = (const int*)d_in[2];
    const float* freqs = (const float*)d_in[3];
    const float* Wq = (const float*)d_in[5];
    const float* bq = (const float*)d_in[6];
    const float* Wk = (const float*)d_in[7];
    const float* bk = (const float*)d_in[8];
    const float* Wv = (const float*)d_in[9];
    const float* bv = (const float*)d_in[10];
    const float* Wo = (const float*)d_in[11];
    const float* bo = (const float*)d_in[12];
    const float* gq = (const float*)d_in[13];
    const float* gk = (const float*)d_in[14];
    float* out = (float*)d_out;

    char* w = (char*)d_ws;
    u16* xb    = (u16*)w; w += (size_t)S * DIM * 2;
    u16* qkv   = (u16*)w; w += (size_t)S * NQKV * 2;
    u16* Wqkvb = (u16*)w; w += (size_t)3 * DIM * DIM * 2;
    u16* Wob   = (u16*)w; w += (size_t)DIM * DIM * 2;
    u16* ab    = (u16*)w; w += (size_t)S * DIM * 2;   // O-partial 0, combined in place
    u16* O1    = (u16*)w; w += (size_t)S * DIM * 2;
    float* cosT = (float*)w; w += (size_t)S * CHALF * 4;
    float* sinT = (float*)w; w += (size_t)S * CHALF * 4;
    float* lT  = (float*)w; w += (size_t)2 * HEADS * S * 4;
    u16* vt = Wqkvb;  // alias: QKV weights dead after QKV GEMM; vt written after

    const float qscale = 0.08838834764831845f * 1.44269504088896341f;  // HD^-0.5 * log2(e)

    const int N4X = S * DIM / 4, N4W = DIM * DIM / 4;
    k_cvt_all<<<(N4X + 4 * N4W) / 256, 256, 0, stream>>>(
        (const float4*)x, (const float4*)Wq, (const float4*)Wk, (const float4*)Wv, (const float4*)Wo,
        (ushort4*)xb, (ushort4*)Wqkvb, (ushort4*)Wob);
    k_tables<<<(S * CHALF + 255) / 256, 256, 0, stream>>>(freqs, grid_sizes, cosT, sinT);

    k_gemm<1, 1><<<dim3(NQKV / 128, S / 128), 256, 0, stream>>>(
        xb, Wqkvb, bq, bk, bv, qkv, NQKV, DIM, NQKV);

    k_normrope<<<dim3(S, 2), 256, 0, stream>>>(qkv, gq, gk, cosT, sinT, qscale);

    k_transpose<<<dim3(DIM / 32, S / 32), dim3(32, 8), 0, stream>>>(qkv + 2 * DIM, vt);

    k_attn<<<dim3(S / 128, HEADS, 2), 256, 0, stream>>>(qkv, vt, ab, O1, lT, seq_lens);

    k_combine<<<S, 384, 0, stream>>>(ab, O1, lT);

    k_gemm<0, 0><<<dim3(DIM / 128, S / 128), 256, 0, stream>>>(
        ab, Wob, bo, bo, bo, out, DIM, DIM, DIM);
}